// Round 6
// baseline (923.831 us; speedup 1.0000x reference)
//
#include <hip/hip_runtime.h>
#include <hip/hip_fp16.h>

#define NPT 4096
#define DM 128
#define ROUNDS 12
#define INF64 0xFFFFFFFFFFFFFFFFull

typedef _Float16 f16x8 __attribute__((ext_vector_type(8)));
typedef _Float16 f16x2 __attribute__((ext_vector_type(2)));
typedef float f32x4 __attribute__((ext_vector_type(4)));

// ---------------- init: comp[i]=i, compbest=INF, w=0, cnt=0, done=0, rep=0 ----------------
__global__ __launch_bounds__(256) void init_kernel(unsigned* __restrict__ comp,
                                                   unsigned long long* __restrict__ compbest,
                                                   float* __restrict__ w,
                                                   unsigned* __restrict__ cnt,
                                                   unsigned* __restrict__ done,
                                                   float* __restrict__ rep) {
    int i = blockIdx.x * blockDim.x + threadIdx.x;   // 0..8191
    comp[i] = (unsigned)(i & (NPT - 1));
    compbest[i] = INF64;
    w[i] = 0.0f;
    if (i < 2) cnt[i] = 0u;
    if (i < 2 * ROUNDS) done[i] = 0u;
    if (i == 0) rep[0] = 0.0f;
}

// ---------------- prep: fp32 -> fp16 rows + consistent squared norms ----------------
__global__ __launch_bounds__(256) void prep_kernel(const float* __restrict__ x1,
                                                   const float* __restrict__ x2,
                                                   _Float16* __restrict__ Xh,
                                                   float* __restrict__ norms) {
    const int wv = threadIdx.x >> 6, ln = threadIdx.x & 63;
    const int row = blockIdx.x * 4 + wv;             // 0..8191
    const float* src = (row < NPT) ? (x1 + (size_t)row * DM)
                                   : (x2 + (size_t)(row - NPT) * DM);
    float2 v = *(const float2*)(src + ln * 2);
    _Float16 h0 = (_Float16)v.x, h1 = (_Float16)v.y;
    f16x2 p; p[0] = h0; p[1] = h1;
    *(f16x2*)(Xh + (size_t)row * DM + ln * 2) = p;
    float a = (float)h0, b = (float)h1;
    float s = a * a + b * b;
    #pragma unroll
    for (int off = 32; off > 0; off >>= 1) s += __shfl_down(s, off);
    if (ln == 0) norms[row] = s;
}

// ---------------- Gram via fp16 MFMA, full-square tiles, LDS-staged coalesced writes ----------------
// grid (1024, 2), block 256 (4 waves, each 64x64 of a 128x128 tile)
__global__ __launch_bounds__(256) void gram_kernel(const _Float16* __restrict__ Xh,
                                                   const float* __restrict__ norms,
                                                   __half* __restrict__ Dall) {
    const int mat = blockIdx.y;
    const _Float16* __restrict__ X = Xh + (size_t)mat * NPT * DM;
    const float* __restrict__ nrm = norms + mat * NPT;
    __half* __restrict__ D = Dall + (size_t)mat * NPT * NPT;

    const int I = blockIdx.x >> 5;     // tile row 0..31
    const int J = blockIdx.x & 31;     // tile col 0..31

    __shared__ _Float16 tile[128 * 136];   // pad 136: rows 272B = 16B-aligned

    const int t = threadIdx.x;
    const int wv = t >> 6, ln = t & 63;
    const int rloc = (wv >> 1) * 64;
    const int cloc = (wv & 1) * 64;
    const int rowBase = I * 128 + rloc;
    const int colBase = J * 128 + cloc;
    const int lr = ln & 15;     // lane's row/col within fragment
    const int kg = ln >> 4;     // lane's k-group (8 elems)

    f32x4 acc[4][4];
    #pragma unroll
    for (int m = 0; m < 4; ++m)
        #pragma unroll
        for (int n = 0; n < 4; ++n)
            acc[m][n] = (f32x4){0.f, 0.f, 0.f, 0.f};

    #pragma unroll
    for (int ks = 0; ks < 4; ++ks) {
        const int k0 = ks * 32 + kg * 8;
        f16x8 a[4], b[4];
        #pragma unroll
        for (int m = 0; m < 4; ++m)
            a[m] = *(const f16x8*)(X + (size_t)(rowBase + m * 16 + lr) * DM + k0);
        #pragma unroll
        for (int n = 0; n < 4; ++n)
            b[n] = *(const f16x8*)(X + (size_t)(colBase + n * 16 + lr) * DM + k0);
        #pragma unroll
        for (int m = 0; m < 4; ++m)
            #pragma unroll
            for (int n = 0; n < 4; ++n)
                acc[m][n] = __builtin_amdgcn_mfma_f32_16x16x32_f16(a[m], b[n], acc[m][n], 0, 0, 0);
    }

    float nr[16], nc[4];
    #pragma unroll
    for (int m = 0; m < 4; ++m)
        #pragma unroll
        for (int q = 0; q < 4; ++q)
            nr[m * 4 + q] = nrm[rowBase + m * 16 + kg * 4 + q];
    #pragma unroll
    for (int n = 0; n < 4; ++n) nc[n] = nrm[colBase + n * 16 + lr];

    // C/D layout: col = lane&15, row = (lane>>4)*4 + reg
    #pragma unroll
    for (int m = 0; m < 4; ++m) {
        #pragma unroll
        for (int n = 0; n < 4; ++n) {
            #pragma unroll
            for (int q = 0; q < 4; ++q) {
                const int rl = rloc + m * 16 + kg * 4 + q;
                const int cl = cloc + n * 16 + lr;
                float d2 = nr[m * 4 + q] + nc[n] - 2.0f * acc[m][n][q];
                float d = sqrtf(fmaxf(d2, 0.0f) + 1e-12f);
                tile[rl * 136 + cl] = (_Float16)d;
            }
        }
    }
    __syncthreads();

    // coalesced write-out: 2048 chunks of 16B; lane -> 16B contiguous
    const int tileRow0 = I * 128;
    #pragma unroll
    for (int it = 0; it < 8; ++it) {
        int idx = it * 256 + t;          // 0..2047
        int row = idx >> 4;              // 0..127
        int ch = idx & 15;               // 16B chunk within 256B row
        *(uint4*)(&D[(size_t)(tileRow0 + row) * NPT + J * 128 + ch * 8]) =
            *(const uint4*)(&tile[row * 136 + ch * 8]);
    }
}

// ---------------- Boruvka round: phase A (all blocks) + phase CD (last block per matrix) ----------------
// grid (256, 2), block 1024 (16 waves, 1 node per wave)
__global__ __launch_bounds__(1024) void boruvka_round(const __half* __restrict__ Dall,
                                                      unsigned* __restrict__ compAll,
                                                      unsigned long long* __restrict__ compbestAll,
                                                      float* __restrict__ wAll,
                                                      unsigned* __restrict__ cntAll,
                                                      unsigned* __restrict__ doneAll,
                                                      int r) {
    const int mat = blockIdx.y;
    if (cntAll[mat] >= NPT - 1u) return;              // MST complete: no-op round
    const __half* __restrict__ D = Dall + (size_t)mat * NPT * NPT;
    unsigned* __restrict__ comp = compAll + mat * NPT;
    unsigned long long* __restrict__ compbest = compbestAll + mat * NPT;
    float* __restrict__ w = wAll + mat * NPT;
    unsigned* __restrict__ cnt = cntAll + mat;

    __shared__ unsigned short sh16[NPT];   // lcomp (phase A) / par (phase CD)
    __shared__ int lastFlag;
    const int t = threadIdx.x, wv = t >> 6, ln = t & 63;

    for (int i = t; i < NPT; i += 1024) sh16[i] = (unsigned short)comp[i];
    __syncthreads();

    // ---- phase A: per-node min outgoing edge ----
    const int node = blockIdx.x * 16 + wv;
    const unsigned ci = sh16[node];
    const unsigned* __restrict__ row = (const unsigned*)(D + (size_t)node * NPT);

    unsigned best = 0xFFFFFFFFu;
    #pragma unroll
    for (int k = 0; k < 8; ++k) {
        const int jb = k * 512 + ln * 8;
        uint4 dv = *(const uint4*)(row + (jb >> 1));
        uint4 cv = *(const uint4*)&sh16[jb];
        const unsigned dp[4] = {dv.x, dv.y, dv.z, dv.w};
        const unsigned cp[4] = {cv.x, cv.y, cv.z, cv.w};
        #pragma unroll
        for (int q = 0; q < 4; ++q) {
            int j0 = jb + q * 2;
            unsigned k0 = (dp[q] << 16) | (unsigned)j0;
            unsigned k1 = (dp[q] & 0xFFFF0000u) | (unsigned)(j0 + 1);
            if ((cp[q] & 0xFFFFu) == ci) k0 = 0xFFFFFFFFu;
            if ((cp[q] >> 16) == ci)     k1 = 0xFFFFFFFFu;
            unsigned m = k0 < k1 ? k0 : k1;
            best = best < m ? best : m;
        }
    }
    #pragma unroll
    for (int off = 32; off > 0; off >>= 1) {
        unsigned o = __shfl_down(best, off);
        best = best < o ? best : o;
    }
    if (ln == 0 && best != 0xFFFFFFFFu) {
        unsigned h = best >> 16;
        unsigned j = best & 0xFFFFu;
        unsigned mn = (unsigned)node < j ? (unsigned)node : j;
        unsigned mx = (unsigned)node < j ? j : (unsigned)node;
        unsigned long long key64 = ((unsigned long long)h << 48) |
                                   ((unsigned long long)mn << 32) |
                                   ((unsigned long long)mx << 16) |
                                   (unsigned long long)j;
        atomicMin(&compbest[ci], key64);
    }

    // ---- last-block handoff ----
    __threadfence();
    if (t == 0)
        lastFlag = (atomicAdd(&doneAll[r * 2 + mat], 1u) == 255u) ? 1 : 0;
    __syncthreads();
    if (!lastFlag) return;

    // ---- phase CD (single block): union roots, collect weights, pointer-jump, reset ----
    // compbest written by other blocks THIS dispatch -> read via RMW no-op (coherent).
    for (int c = t; c < NPT; c += 1024) {
        unsigned p = (unsigned)c;
        if (comp[c] == (unsigned)c) {
            unsigned long long key = atomicMin(&compbest[c], INF64);
            if (key != INF64) {
                unsigned jout = (unsigned)(key & 0xFFFFull);
                unsigned c2 = comp[jout];
                unsigned long long k2 = atomicMin(&compbest[c2], INF64);
                bool mutual = (k2 >> 16) == (key >> 16);     // same undirected edge
                if (!mutual || (unsigned)c < c2) {
                    unsigned short hb = (unsigned short)(key >> 48);
                    float wvv = fminf(__half2float(__ushort_as_half(hb)), 100.0f);
                    unsigned slot = atomicAdd(cnt, 1u);
                    w[slot] = wvv;
                }
                p = (mutual && (unsigned)c < c2) ? (unsigned)c : c2;
            }
        }
        sh16[c] = (unsigned short)p;
    }
    __syncthreads();

    for (int it = 0; it < 12; ++it) {
        unsigned short np[4];
        #pragma unroll
        for (int q = 0; q < 4; ++q) np[q] = sh16[sh16[t + q * 1024]];
        __syncthreads();
        #pragma unroll
        for (int q = 0; q < 4; ++q) sh16[t + q * 1024] = np[q];
        __syncthreads();
    }

    for (int c = t; c < NPT; c += 1024) {
        comp[c] = sh16[comp[c]];
        compbest[c] = INF64;
    }
}

// ---------------- representation loss partial sums ----------------
__global__ __launch_bounds__(256) void rep_kernel(const float4* __restrict__ x1,
                                                  const float4* __restrict__ x2,
                                                  float* __restrict__ acc) {
    int idx = blockIdx.x * blockDim.x + threadIdx.x;
    int stride = gridDim.x * blockDim.x;
    float s = 0.f;
    for (int i = idx; i < NPT * DM / 4; i += stride) {
        float4 a = x1[i], b = x2[i];
        float d0 = a.x - b.x, d1 = a.y - b.y, d2 = a.z - b.z, d3 = a.w - b.w;
        s += d0 * d0 + d1 * d1 + d2 * d2 + d3 * d3;
    }
    #pragma unroll
    for (int off = 32; off > 0; off >>= 1) s += __shfl_down(s, off);
    __shared__ float partial[4];
    int wv = threadIdx.x >> 6, ln = threadIdx.x & 63;
    if (ln == 0) partial[wv] = s;
    __syncthreads();
    if (threadIdx.x == 0) {
        float tot = partial[0] + partial[1] + partial[2] + partial[3];
        atomicAdd(acc, tot);
    }
}

// ---------------- sort one weight array per block (bitonic, LDS) ----------------
__global__ __launch_bounds__(1024) void sort_kernel(float* __restrict__ wAll) {
    float* __restrict__ w = wAll + blockIdx.x * NPT;
    __shared__ float s[NPT];
    const int t = threadIdx.x;
    for (int i = t; i < NPT; i += 1024) s[i] = w[i];
    __syncthreads();

    for (int k = 2; k <= NPT; k <<= 1) {
        for (int j = k >> 1; j > 0; j >>= 1) {
            for (int i = t; i < NPT; i += 1024) {
                int ixj = i ^ j;
                if (ixj > i) {
                    bool up = (i & k) == 0;
                    float a = s[i], b = s[ixj];
                    if ((a > b) == up) { s[i] = b; s[ixj] = a; }
                }
            }
            __syncthreads();
        }
    }
    for (int i = t; i < NPT; i += 1024) w[i] = s[i];
}

// ---------------- W1 diff-sum + combine ----------------
__global__ __launch_bounds__(1024) void final2_kernel(const float* __restrict__ w,
                                                      const float* __restrict__ rep,
                                                      float* __restrict__ out) {
    const int t = threadIdx.x;
    float loc = 0.f;
    for (int i = t; i < NPT; i += 1024) loc += fabsf(w[i] - w[NPT + i]);
    #pragma unroll
    for (int off = 32; off > 0; off >>= 1) loc += __shfl_down(loc, off);
    __shared__ float reds[16];
    int wv = t >> 6, ln = t & 63;
    if (ln == 0) reds[wv] = loc;
    __syncthreads();
    if (t == 0) {
        float tot = 0.f;
        #pragma unroll
        for (int i = 0; i < 16; ++i) tot += reds[i];
        out[0] = tot + rep[0] * (1.0f / (NPT * DM));
    }
}

extern "C" void kernel_launch(void* const* d_in, const int* in_sizes, int n_in,
                              void* d_out, int out_size, void* d_ws, size_t ws_size,
                              hipStream_t stream) {
    const float* x1 = (const float*)d_in[0];
    const float* x2 = (const float*)d_in[1];
    float* out = (float*)d_out;

    char* ws = (char*)d_ws;
    __half* D = (__half*)ws;                                           // 64 MB
    size_t off = (size_t)2 * NPT * NPT * sizeof(__half);
    _Float16* Xh = (_Float16*)(ws + off);                              // 2 MB
    off += (size_t)2 * NPT * DM * sizeof(_Float16);
    float* norms = (float*)(ws + off);                                 // 32 KB
    off += (size_t)2 * NPT * sizeof(float);
    unsigned long long* compbest = (unsigned long long*)(ws + off);    // 64 KB
    off += (size_t)2 * NPT * sizeof(unsigned long long);
    float* w = (float*)(ws + off);                                     // 32 KB
    off += (size_t)2 * NPT * sizeof(float);
    unsigned* comp = (unsigned*)(ws + off);                            // 32 KB
    off += (size_t)2 * NPT * sizeof(unsigned);
    unsigned* cnt = (unsigned*)(ws + off);                             // 8 B
    off += 2 * sizeof(unsigned);
    unsigned* done = (unsigned*)(ws + off);                            // 96 B
    off += 2 * ROUNDS * sizeof(unsigned);
    float* rep = (float*)(ws + off);

    init_kernel<<<2 * NPT / 256, 256, 0, stream>>>(comp, compbest, w, cnt, done, rep);

    prep_kernel<<<2 * NPT / 4, 256, 0, stream>>>(x1, x2, Xh, norms);

    gram_kernel<<<dim3(1024, 2), 256, 0, stream>>>(Xh, norms, D);

    for (int r = 0; r < ROUNDS; ++r)
        boruvka_round<<<dim3(256, 2), 1024, 0, stream>>>(D, comp, compbest, w, cnt, done, r);

    rep_kernel<<<256, 256, 0, stream>>>((const float4*)x1, (const float4*)x2, rep);

    sort_kernel<<<2, 1024, 0, stream>>>(w);

    final2_kernel<<<1, 1024, 0, stream>>>(w, rep, out);
}

// Round 7
// 340.543 us; speedup vs baseline: 2.7128x; 2.7128x over previous
//
#include <hip/hip_runtime.h>
#include <hip/hip_fp16.h>

#define NPT 4096
#define DM 128
#define ROUNDS 12
#define INF64 0xFFFFFFFFFFFFFFFFull

typedef _Float16 f16x8 __attribute__((ext_vector_type(8)));
typedef _Float16 f16x2 __attribute__((ext_vector_type(2)));
typedef float f32x4 __attribute__((ext_vector_type(4)));

// ---------------- init: comp[i]=i, compbest=INF, w=0, cnt=0, rep=0 ----------------
__global__ __launch_bounds__(256) void init_kernel(unsigned* __restrict__ comp,
                                                   unsigned long long* __restrict__ compbest,
                                                   float* __restrict__ w,
                                                   unsigned* __restrict__ cnt,
                                                   float* __restrict__ rep) {
    int i = blockIdx.x * blockDim.x + threadIdx.x;   // 0..8191
    comp[i] = (unsigned)(i & (NPT - 1));
    compbest[i] = INF64;
    w[i] = 0.0f;
    if (i < 2) cnt[i] = 0u;
    if (i == 0) rep[0] = 0.0f;
}

// ---------------- prep: fp32 -> fp16 rows + consistent squared norms ----------------
__global__ __launch_bounds__(256) void prep_kernel(const float* __restrict__ x1,
                                                   const float* __restrict__ x2,
                                                   _Float16* __restrict__ Xh,
                                                   float* __restrict__ norms) {
    const int wv = threadIdx.x >> 6, ln = threadIdx.x & 63;
    const int row = blockIdx.x * 4 + wv;             // 0..8191
    const float* src = (row < NPT) ? (x1 + (size_t)row * DM)
                                   : (x2 + (size_t)(row - NPT) * DM);
    float2 v = *(const float2*)(src + ln * 2);
    _Float16 h0 = (_Float16)v.x, h1 = (_Float16)v.y;
    f16x2 p; p[0] = h0; p[1] = h1;
    *(f16x2*)(Xh + (size_t)row * DM + ln * 2) = p;
    float a = (float)h0, b = (float)h1;
    float s = a * a + b * b;
    #pragma unroll
    for (int off = 32; off > 0; off >>= 1) s += __shfl_down(s, off);
    if (ln == 0) norms[row] = s;
}

// ---------------- Gram via fp16 MFMA, full-square tiles, LDS-staged coalesced writes ----------------
// grid (1024, 2), block 256 (4 waves, each 64x64 of a 128x128 tile)
__global__ __launch_bounds__(256) void gram_kernel(const _Float16* __restrict__ Xh,
                                                   const float* __restrict__ norms,
                                                   __half* __restrict__ Dall) {
    const int mat = blockIdx.y;
    const _Float16* __restrict__ X = Xh + (size_t)mat * NPT * DM;
    const float* __restrict__ nrm = norms + mat * NPT;
    __half* __restrict__ D = Dall + (size_t)mat * NPT * NPT;

    const int I = blockIdx.x >> 5;     // tile row 0..31
    const int J = blockIdx.x & 31;     // tile col 0..31

    __shared__ _Float16 tile[128 * 136];   // pad 136: rows 272B, 16B-aligned chunks

    const int t = threadIdx.x;
    const int wv = t >> 6, ln = t & 63;
    const int rloc = (wv >> 1) * 64;
    const int cloc = (wv & 1) * 64;
    const int rowBase = I * 128 + rloc;
    const int colBase = J * 128 + cloc;
    const int lr = ln & 15;     // lane's row/col within fragment
    const int kg = ln >> 4;     // lane's k-group (8 elems)

    f32x4 acc[4][4];
    #pragma unroll
    for (int m = 0; m < 4; ++m)
        #pragma unroll
        for (int n = 0; n < 4; ++n)
            acc[m][n] = (f32x4){0.f, 0.f, 0.f, 0.f};

    #pragma unroll
    for (int ks = 0; ks < 4; ++ks) {
        const int k0 = ks * 32 + kg * 8;
        f16x8 a[4], b[4];
        #pragma unroll
        for (int m = 0; m < 4; ++m)
            a[m] = *(const f16x8*)(X + (size_t)(rowBase + m * 16 + lr) * DM + k0);
        #pragma unroll
        for (int n = 0; n < 4; ++n)
            b[n] = *(const f16x8*)(X + (size_t)(colBase + n * 16 + lr) * DM + k0);
        #pragma unroll
        for (int m = 0; m < 4; ++m)
            #pragma unroll
            for (int n = 0; n < 4; ++n)
                acc[m][n] = __builtin_amdgcn_mfma_f32_16x16x32_f16(a[m], b[n], acc[m][n], 0, 0, 0);
    }

    float nr[16], nc[4];
    #pragma unroll
    for (int m = 0; m < 4; ++m)
        #pragma unroll
        for (int q = 0; q < 4; ++q)
            nr[m * 4 + q] = nrm[rowBase + m * 16 + kg * 4 + q];
    #pragma unroll
    for (int n = 0; n < 4; ++n) nc[n] = nrm[colBase + n * 16 + lr];

    // C/D layout: col = lane&15, row = (lane>>4)*4 + reg
    #pragma unroll
    for (int m = 0; m < 4; ++m) {
        #pragma unroll
        for (int n = 0; n < 4; ++n) {
            #pragma unroll
            for (int q = 0; q < 4; ++q) {
                const int rl = rloc + m * 16 + kg * 4 + q;
                const int cl = cloc + n * 16 + lr;
                float d2 = nr[m * 4 + q] + nc[n] - 2.0f * acc[m][n][q];
                float d = sqrtf(fmaxf(d2, 0.0f) + 1e-12f);
                tile[rl * 136 + cl] = (_Float16)d;
            }
        }
    }
    __syncthreads();

    // coalesced write-out: 2048 chunks of 16B; 16 consecutive lanes cover one 256B row
    const int tileRow0 = I * 128;
    #pragma unroll
    for (int it = 0; it < 8; ++it) {
        int idx = it * 256 + t;          // 0..2047
        int row = idx >> 4;              // 0..127
        int ch = idx & 15;               // 16B chunk within 256B row
        *(uint4*)(&D[(size_t)(tileRow0 + row) * NPT + J * 128 + ch * 8]) =
            *(const uint4*)(&tile[row * 136 + ch * 8]);
    }
}

// ---------------- Boruvka phase A: per-node min outgoing edge ----------------
// block = 1024 (16 waves), each wave handles one node; grid (NPT/16, 2)
__global__ __launch_bounds__(1024) void boruvka_a(const __half* __restrict__ Dall,
                                                  const unsigned* __restrict__ compAll,
                                                  unsigned long long* __restrict__ compbestAll,
                                                  const unsigned* __restrict__ cnt) {
    const int mat = blockIdx.y;
    if (cnt[mat] >= NPT - 1u) return;                 // MST complete: no-op round
    const __half* __restrict__ D = Dall + (size_t)mat * NPT * NPT;
    const unsigned* __restrict__ comp = compAll + mat * NPT;
    unsigned long long* __restrict__ compbest = compbestAll + mat * NPT;

    __shared__ unsigned short lcomp[NPT];
    const int t = threadIdx.x;
    for (int i = t; i < NPT; i += 1024) lcomp[i] = (unsigned short)comp[i];
    __syncthreads();

    const int wv = t >> 6, ln = t & 63;
    const int node = blockIdx.x * 16 + wv;
    const unsigned ci = lcomp[node];
    const unsigned* __restrict__ row = (const unsigned*)(D + (size_t)node * NPT);

    unsigned best = 0xFFFFFFFFu;
    #pragma unroll
    for (int k = 0; k < 8; ++k) {
        const int jb = k * 512 + ln * 8;
        uint4 dv = *(const uint4*)(row + (jb >> 1));
        uint4 cv = *(const uint4*)&lcomp[jb];
        const unsigned dp[4] = {dv.x, dv.y, dv.z, dv.w};
        const unsigned cp[4] = {cv.x, cv.y, cv.z, cv.w};
        #pragma unroll
        for (int q = 0; q < 4; ++q) {
            int j0 = jb + q * 2;
            unsigned k0 = (dp[q] << 16) | (unsigned)j0;
            unsigned k1 = (dp[q] & 0xFFFF0000u) | (unsigned)(j0 + 1);
            if ((cp[q] & 0xFFFFu) == ci) k0 = 0xFFFFFFFFu;
            if ((cp[q] >> 16) == ci)     k1 = 0xFFFFFFFFu;
            unsigned m = k0 < k1 ? k0 : k1;
            best = best < m ? best : m;
        }
    }
    #pragma unroll
    for (int off = 32; off > 0; off >>= 1) {
        unsigned o = __shfl_down(best, off);
        best = best < o ? best : o;
    }
    if (ln == 0 && best != 0xFFFFFFFFu) {
        unsigned h = best >> 16;
        unsigned j = best & 0xFFFFu;
        unsigned mn = (unsigned)node < j ? (unsigned)node : j;
        unsigned mx = (unsigned)node < j ? j : (unsigned)node;
        unsigned long long key64 = ((unsigned long long)h << 48) |
                                   ((unsigned long long)mn << 32) |
                                   ((unsigned long long)mx << 16) |
                                   (unsigned long long)j;
        atomicMin(&compbest[ci], key64);
    }
}

// ---------------- Boruvka phase C+D: union, collect weights, pointer-jump, reset ----------------
__global__ __launch_bounds__(1024) void boruvka_cd(unsigned* __restrict__ compAll,
                                                   unsigned long long* __restrict__ compbestAll,
                                                   float* __restrict__ wAll,
                                                   unsigned* __restrict__ cntAll) {
    const int mat = blockIdx.x;
    if (cntAll[mat] >= NPT - 1u) return;
    unsigned* __restrict__ comp = compAll + mat * NPT;
    unsigned long long* __restrict__ compbest = compbestAll + mat * NPT;
    float* __restrict__ w = wAll + mat * NPT;
    unsigned* __restrict__ cnt = cntAll + mat;

    __shared__ unsigned short par[NPT];
    const int t = threadIdx.x;

    for (int c = t; c < NPT; c += 1024) {
        unsigned p = (unsigned)c;
        unsigned long long key = compbest[c];
        if (comp[c] == (unsigned)c && key != INF64) {
            unsigned jout = (unsigned)(key & 0xFFFFull);
            unsigned c2 = comp[jout];
            unsigned long long k2 = compbest[c2];
            bool mutual = (k2 >> 16) == (key >> 16);     // same undirected edge
            if (!mutual || (unsigned)c < c2) {
                unsigned short hb = (unsigned short)(key >> 48);
                float wv = fminf(__half2float(__ushort_as_half(hb)), 100.0f);
                unsigned slot = atomicAdd(cnt, 1u);
                w[slot] = wv;
            }
            p = (mutual && (unsigned)c < c2) ? (unsigned)c : c2;
        }
        par[c] = (unsigned short)p;
    }
    __syncthreads();

    for (int it = 0; it < 12; ++it) {
        unsigned short np[4];
        #pragma unroll
        for (int q = 0; q < 4; ++q) np[q] = par[par[t + q * 1024]];
        __syncthreads();
        #pragma unroll
        for (int q = 0; q < 4; ++q) par[t + q * 1024] = np[q];
        __syncthreads();
    }

    for (int c = t; c < NPT; c += 1024) {
        comp[c] = par[comp[c]];
        compbest[c] = INF64;
    }
}

// ---------------- representation loss partial sums ----------------
__global__ __launch_bounds__(256) void rep_kernel(const float4* __restrict__ x1,
                                                  const float4* __restrict__ x2,
                                                  float* __restrict__ acc) {
    int idx = blockIdx.x * blockDim.x + threadIdx.x;
    int stride = gridDim.x * blockDim.x;
    float s = 0.f;
    for (int i = idx; i < NPT * DM / 4; i += stride) {
        float4 a = x1[i], b = x2[i];
        float d0 = a.x - b.x, d1 = a.y - b.y, d2 = a.z - b.z, d3 = a.w - b.w;
        s += d0 * d0 + d1 * d1 + d2 * d2 + d3 * d3;
    }
    #pragma unroll
    for (int off = 32; off > 0; off >>= 1) s += __shfl_down(s, off);
    __shared__ float partial[4];
    int wv = threadIdx.x >> 6, ln = threadIdx.x & 63;
    if (ln == 0) partial[wv] = s;
    __syncthreads();
    if (threadIdx.x == 0) {
        float tot = partial[0] + partial[1] + partial[2] + partial[3];
        atomicAdd(acc, tot);
    }
}

// ---------------- sort one weight array per block (bitonic, LDS) ----------------
__global__ __launch_bounds__(1024) void sort_kernel(float* __restrict__ wAll) {
    float* __restrict__ w = wAll + blockIdx.x * NPT;
    __shared__ float s[NPT];
    const int t = threadIdx.x;
    for (int i = t; i < NPT; i += 1024) s[i] = w[i];
    __syncthreads();

    for (int k = 2; k <= NPT; k <<= 1) {
        for (int j = k >> 1; j > 0; j >>= 1) {
            for (int i = t; i < NPT; i += 1024) {
                int ixj = i ^ j;
                if (ixj > i) {
                    bool up = (i & k) == 0;
                    float a = s[i], b = s[ixj];
                    if ((a > b) == up) { s[i] = b; s[ixj] = a; }
                }
            }
            __syncthreads();
        }
    }
    for (int i = t; i < NPT; i += 1024) w[i] = s[i];
}

// ---------------- W1 diff-sum + combine ----------------
__global__ __launch_bounds__(1024) void final2_kernel(const float* __restrict__ w,
                                                      const float* __restrict__ rep,
                                                      float* __restrict__ out) {
    const int t = threadIdx.x;
    float loc = 0.f;
    for (int i = t; i < NPT; i += 1024) loc += fabsf(w[i] - w[NPT + i]);
    #pragma unroll
    for (int off = 32; off > 0; off >>= 1) loc += __shfl_down(loc, off);
    __shared__ float reds[16];
    int wv = t >> 6, ln = t & 63;
    if (ln == 0) reds[wv] = loc;
    __syncthreads();
    if (t == 0) {
        float tot = 0.f;
        #pragma unroll
        for (int i = 0; i < 16; ++i) tot += reds[i];
        out[0] = tot + rep[0] * (1.0f / (NPT * DM));
    }
}

extern "C" void kernel_launch(void* const* d_in, const int* in_sizes, int n_in,
                              void* d_out, int out_size, void* d_ws, size_t ws_size,
                              hipStream_t stream) {
    const float* x1 = (const float*)d_in[0];
    const float* x2 = (const float*)d_in[1];
    float* out = (float*)d_out;

    char* ws = (char*)d_ws;
    __half* D = (__half*)ws;                                           // 64 MB
    size_t off = (size_t)2 * NPT * NPT * sizeof(__half);
    _Float16* Xh = (_Float16*)(ws + off);                              // 2 MB
    off += (size_t)2 * NPT * DM * sizeof(_Float16);
    float* norms = (float*)(ws + off);                                 // 32 KB
    off += (size_t)2 * NPT * sizeof(float);
    unsigned long long* compbest = (unsigned long long*)(ws + off);    // 64 KB
    off += (size_t)2 * NPT * sizeof(unsigned long long);
    float* w = (float*)(ws + off);                                     // 32 KB
    off += (size_t)2 * NPT * sizeof(float);
    unsigned* comp = (unsigned*)(ws + off);                            // 32 KB
    off += (size_t)2 * NPT * sizeof(unsigned);
    unsigned* cnt = (unsigned*)(ws + off);                             // 16 B
    off += 4 * sizeof(unsigned);
    float* rep = (float*)(ws + off);

    init_kernel<<<2 * NPT / 256, 256, 0, stream>>>(comp, compbest, w, cnt, rep);

    prep_kernel<<<2 * NPT / 4, 256, 0, stream>>>(x1, x2, Xh, norms);

    gram_kernel<<<dim3(1024, 2), 256, 0, stream>>>(Xh, norms, D);

    for (int r = 0; r < ROUNDS; ++r) {
        boruvka_a<<<dim3(NPT / 16, 2), 1024, 0, stream>>>(D, comp, compbest, cnt);
        boruvka_cd<<<2, 1024, 0, stream>>>(comp, compbest, w, cnt);
    }

    rep_kernel<<<256, 256, 0, stream>>>((const float4*)x1, (const float4*)x2, rep);

    sort_kernel<<<2, 1024, 0, stream>>>(w);

    final2_kernel<<<1, 1024, 0, stream>>>(w, rep, out);
}